// Round 1
// baseline (236.187 us; speedup 1.0000x reference)
//
#include <hip/hip_runtime.h>
#include <math.h>

// LDSLoss: weighted MSE with label-distribution-smoothing weights.
// One streaming pass over input/target (128 MB) + tiny table gathers.
//
//   mean = scaling * ( sum_{finite} w_i*sq_i + finite_max * sum_{inf} sq_i ) / (2N)
//
// where sq_i = (in0-t0)^2 + (in1-t1)^2, w_i = 1/smoothed[i0,i1].

#define BLOCK 256
#define GRID_CAP 2048   // 8 blocks/CU * 256 CU -> full occupancy, grid-stride rest

__device__ __forceinline__ int bin_idx(const float* __restrict__ bins,
                                       int nedges, float x, int nbm1) {
    // searchsorted(bins, x, side='right'): first idx with x < bins[idx]
    int lo = 0, hi = nedges;
    while (lo < hi) {
        int mid = (lo + hi) >> 1;
        if (x < bins[mid]) hi = mid; else lo = mid + 1;
    }
    int idx = lo - 1;
    idx = idx < 0 ? 0 : idx;
    return idx > nbm1 ? nbm1 : idx;
}

__global__ void __launch_bounds__(BLOCK)
lds_loss_main(const float* __restrict__ input,
              const float* __restrict__ target,
              const float* __restrict__ smoothed,
              const float* __restrict__ bins0,
              const float* __restrict__ bins1,
              int nb, long long n,
              double* __restrict__ accA,
              double* __restrict__ accB,
              unsigned int* __restrict__ accM)
{
    extern __shared__ float sbins[];           // [nb+1] bins0 | [nb+1] bins1
    float* sb0 = sbins;
    float* sb1 = sbins + (nb + 1);
    for (int i = threadIdx.x; i < nb + 1; i += BLOCK) {
        sb0[i] = bins0[i];
        sb1[i] = bins1[i];
    }
    __syncthreads();

    double a = 0.0, b = 0.0;
    float  m = 0.0f;                           // weights are > 0

    const long long npair = n >> 1;            // 2 samples (16 B) per iteration
    const float4* in4 = (const float4*)input;
    const float4* tg4 = (const float4*)target;
    const long long stride = (long long)gridDim.x * BLOCK;

    for (long long p = (long long)blockIdx.x * BLOCK + threadIdx.x;
         p < npair; p += stride) {
        float4 in = in4[p];
        float4 tg = tg4[p];

        {   // sample 2p
            float d0 = in.x - tg.x, d1 = in.y - tg.y;
            float sq = d0 * d0 + d1 * d1;
            int i0 = bin_idx(sb0, nb + 1, tg.x, nb - 1);
            int i1 = bin_idx(sb1, nb + 1, tg.y, nb - 1);
            float w = 1.0f / smoothed[i0 * nb + i1];
            if (isinf(w)) { b += (double)sq; }
            else          { a += (double)w * (double)sq; m = fmaxf(m, w); }
        }
        {   // sample 2p+1
            float d0 = in.z - tg.z, d1 = in.w - tg.w;
            float sq = d0 * d0 + d1 * d1;
            int i0 = bin_idx(sb0, nb + 1, tg.z, nb - 1);
            int i1 = bin_idx(sb1, nb + 1, tg.w, nb - 1);
            float w = 1.0f / smoothed[i0 * nb + i1];
            if (isinf(w)) { b += (double)sq; }
            else          { a += (double)w * (double)sq; m = fmaxf(m, w); }
        }
    }

    // odd-N tail (not hit for N=8M, kept for generality)
    if ((n & 1) && blockIdx.x == 0 && threadIdx.x == 0) {
        long long i = n - 1;
        float t0 = target[2 * i], t1 = target[2 * i + 1];
        float d0 = input[2 * i] - t0, d1 = input[2 * i + 1] - t1;
        float sq = d0 * d0 + d1 * d1;
        int i0 = bin_idx(sb0, nb + 1, t0, nb - 1);
        int i1 = bin_idx(sb1, nb + 1, t1, nb - 1);
        float w = 1.0f / smoothed[i0 * nb + i1];
        if (isinf(w)) { b += (double)sq; }
        else          { a += (double)w * (double)sq; m = fmaxf(m, w); }
    }

    // wave-64 shuffle reduction
    #pragma unroll
    for (int off = 32; off > 0; off >>= 1) {
        a += __shfl_down(a, off, 64);
        b += __shfl_down(b, off, 64);
        m = fmaxf(m, __shfl_down(m, off, 64));
    }

    __shared__ double sA[BLOCK / 64], sB[BLOCK / 64];
    __shared__ float  sM[BLOCK / 64];
    int wave = threadIdx.x >> 6;
    int lane = threadIdx.x & 63;
    if (lane == 0) { sA[wave] = a; sB[wave] = b; sM[wave] = m; }
    __syncthreads();

    if (threadIdx.x == 0) {
        double ta = 0.0, tb = 0.0; float tm = 0.0f;
        #pragma unroll
        for (int w2 = 0; w2 < BLOCK / 64; ++w2) {
            ta += sA[w2]; tb += sB[w2]; tm = fmaxf(tm, sM[w2]);
        }
        atomicAdd(accA, ta);
        atomicAdd(accB, tb);
        atomicMax(accM, __float_as_uint(tm));   // positive floats: uint order == float order
    }
}

__global__ void lds_loss_final(const double* __restrict__ accA,
                               const double* __restrict__ accB,
                               const unsigned int* __restrict__ accM,
                               const float* __restrict__ scaling,
                               float* __restrict__ out, long long nelem)
{
    double a = *accA, b = *accB;
    float  m = __uint_as_float(*accM);
    double v = (double)(*scaling) * (a + (double)m * b) / (double)nelem;
    *out = (float)v;
}

extern "C" void kernel_launch(void* const* d_in, const int* in_sizes, int n_in,
                              void* d_out, int out_size, void* d_ws, size_t ws_size,
                              hipStream_t stream) {
    const float* input    = (const float*)d_in[0];
    const float* target   = (const float*)d_in[1];
    const float* smoothed = (const float*)d_in[2];
    const float* bins0    = (const float*)d_in[3];
    const float* bins1    = (const float*)d_in[4];
    const float* scaling  = (const float*)d_in[5];

    const long long nelem = in_sizes[0];       // N * 2
    const long long n     = nelem / 2;         // samples
    const int nb          = in_sizes[3] - 1;   // bins (edges - 1)

    double*       accA = (double*)d_ws;
    double*       accB = accA + 1;
    unsigned int* accM = (unsigned int*)(accB + 1);

    // d_ws is poisoned to 0xAA before every launch — zero the accumulators.
    hipMemsetAsync(d_ws, 0, 24, stream);

    long long blocks_needed = (n / 2 + BLOCK - 1) / BLOCK;
    int grid = (int)(blocks_needed < GRID_CAP ? blocks_needed : GRID_CAP);
    if (grid < 1) grid = 1;
    size_t shmem = (size_t)(nb + 1) * 2 * sizeof(float);

    lds_loss_main<<<grid, BLOCK, shmem, stream>>>(
        input, target, smoothed, bins0, bins1, nb, n, accA, accB, accM);
    lds_loss_final<<<1, 1, 0, stream>>>(accA, accB, accM, scaling,
                                        (float*)d_out, nelem);
}